// Round 17
// baseline (3003.738 us; speedup 1.0000x reference)
//
#include <hip/hip_runtime.h>
#include <hip/hip_bf16.h>

// GraphCast-style GNN: encode -> 6x InteractionNetwork -> decode.
// INPUTS fp32, OUTPUT fp32. Internal state bf16.
// State in d_ws, EXACTLY 256,000,000 B: [edge 153.6MB][node 51.2MB][agg 51.2MB].
// Packed bf16 weights + CSR in d_out scratch; decoder overwrites d_out last.
// R17: R12's exact math (precise-div swish, rsqrtf, scrubbed f2bf) +
// LDS overlay (38,912 B) + prefetch depth 3 (triple-buffered A tile,
// steady-state vmcnt(2), counted tail drain).

#define NN 100000
#define NE 300000

typedef __attribute__((ext_vector_type(8))) short bf16x8;
typedef __attribute__((ext_vector_type(8))) unsigned short u16x8;
typedef __attribute__((ext_vector_type(4))) float f32x4;

typedef const __attribute__((address_space(1))) void cg1_t;
typedef __attribute__((address_space(3))) void l3_t;
static __device__ __forceinline__ void gld_lds16(const void* g, void* l) {
  __builtin_amdgcn_global_load_lds((cg1_t*)g, (l3_t*)l, 16, 0, 0);
}

static __device__ __forceinline__ unsigned short f2bf(float f) {
  union { float f; unsigned u; } v; v.f = f;
  unsigned r = v.u + 0x7FFFu + ((v.u >> 16) & 1u);   // RNE
  unsigned short h = (unsigned short)(r >> 16);
  if ((h & 0x7F80u) == 0x7F80u) h = 0;               // safety scrub (R12)
  return h;
}
static __device__ __forceinline__ float bf2f(unsigned short h) {
  union { unsigned u; float f; } v; v.u = ((unsigned)h) << 16;
  return v.f;
}

struct KArgs {
  const float* Xf;             // raw fp32 input (encoder phases)
  unsigned short* nodeB;       // node latent bf16
  unsigned short* edgeB;       // edge latent bf16
  const unsigned short* aggB;  // agg bf16 (node step reads)
  const int* snd;
  const int* rcv;
  const unsigned short* W1p;   // packed W1 (bf16, MFMA frag order)
  const unsigned short* W2p;   // packed W2
  const float* b1;
  const float* b2;
  const float* lns;
  const float* lno;
  float* outF;                 // decoder output (d_out, fp32)
  int M;
};

// Pack fp32 W [Ksrc x N] (zero-pad K to Kpad) into bf16 frag order:
// frag fi=kb*(N/16)+nb; elem (lane,j) = W[kb*32+(lane>>4)*8+j][nb*16+(lane&15)].
__global__ void pack_w(const float* __restrict__ src,
                       unsigned short* __restrict__ dst,
                       int Ksrc, int Kpad, int N) {
  src += (size_t)blockIdx.y * Ksrc * N;
  dst += (size_t)blockIdx.y * Kpad * N;
  int fi = blockIdx.x;
  int nfr = N >> 4;
  int nb = fi % nfr, kb = fi / nfr;
  int t = threadIdx.x;               // 512
  int lane = t >> 3, j = t & 7;
  int k = kb * 32 + ((lane >> 4) * 8) + j;
  int col = nb * 16 + (lane & 15);
  unsigned short v = (k < Ksrc) ? f2bf(src[(size_t)k * N + col]) : (unsigned short)0;
  dst[(size_t)fi * 512 + t] = v;
}

__global__ void zero_ws(uint4* __restrict__ p, int n16) {
  uint4 z = {0u, 0u, 0u, 0u};
  for (int i = blockIdx.x * blockDim.x + threadIdx.x; i < n16;
       i += gridDim.x * blockDim.x)
    p[i] = z;
}

__global__ void hist_k(const int* __restrict__ rcv, int* __restrict__ cnt) {
  int e = blockIdx.x * blockDim.x + threadIdx.x;
  if (e < NE) {
    int r = rcv[e]; r = r < 0 ? 0 : (r > NN - 1 ? NN - 1 : r);
    atomicAdd(&cnt[r], 1);
  }
}

__global__ __launch_bounds__(1024)
void scan_k(const int* __restrict__ cnt, int* __restrict__ off) {
  __shared__ int wsum[16];
  __shared__ int carry_s, tot_s;
  int t = threadIdx.x, lane = t & 63, w = t >> 6;
  if (t == 0) carry_s = 0;
  __syncthreads();
  for (int base = 0; base < NN; base += 1024) {
    int i = base + t;
    int v = (i < NN) ? cnt[i] : 0;
    int incl = v;
    #pragma unroll
    for (int d = 1; d < 64; d <<= 1) {
      int u = __shfl_up(incl, d);
      if (lane >= d) incl += u;
    }
    if (lane == 63) wsum[w] = incl;
    int c0 = carry_s;
    __syncthreads();
    if (t < 16) {
      int s = wsum[t];
      int isc = s;
      #pragma unroll
      for (int d = 1; d < 16; d <<= 1) {
        int u = __shfl_up(isc, d);
        if (t >= d) isc += u;
      }
      wsum[t] = isc - s;               // exclusive wave offset
    }
    __syncthreads();
    int excl = c0 + wsum[w] + incl - v;
    if (i < NN) off[i] = excl;
    if (t == 1023) tot_s = wsum[15] + incl;
    __syncthreads();
    if (t == 0) carry_s += tot_s;
    __syncthreads();
  }
  if (t == 0) off[NN] = carry_s;
}

__global__ void fill_k(const int* __restrict__ rcv, const int* __restrict__ off,
                       int* __restrict__ cnt2, int* __restrict__ eidx) {
  int e = blockIdx.x * blockDim.x + threadIdx.x;
  if (e < NE) {
    int r = rcv[e]; r = r < 0 ? 0 : (r > NN - 1 ? NN - 1 : r);
    int p = off[r] + atomicAdd(&cnt2[r], 1);
    if (p >= 0 && p < NE) eidx[p] = e;
  }
}

// agg[n][t] = sum over incoming edges of edge[e][t]; fp32 accumulate.
__global__ __launch_bounds__(256)
void agg_k(const unsigned short* __restrict__ edge, const int* __restrict__ off,
           const int* __restrict__ eidx, unsigned short* __restrict__ agg) {
  int t = threadIdx.x;
  int n0 = blockIdx.x * 8;
  #pragma unroll 1
  for (int u = 0; u < 8; ++u) {
    int n = n0 + u;
    if (n >= NN) return;
    int s = off[n], e = off[n + 1];
    if (s < 0) s = 0;
    if (e > NE) e = NE;
    float acc = 0.f;
    for (int i = s; i < e; ++i) {
      int eid = eidx[i];
      eid = eid < 0 ? 0 : (eid > NE - 1 ? NE - 1 : eid);
      acc += bf2f(edge[(size_t)eid * 256 + t]);
    }
    agg[(size_t)n * 256 + t] = f2bf(acc);
  }
}

// PHASE: 0 enc_node, 1 enc_edge, 2 edge_step, 3 node_step, 4 decoder.
// 64-row tile, BK=64 phases, 8 waves. A-tile: linear 128B rows, XOR-swizzled
// 16B chunks: chunk c of row r lives at slot (c ^ (r&7)).
template<int PHASE>
__global__ __launch_bounds__(512)
void gnn_kernel(KArgs A) {
  constexpr int K1  = PHASE==0?128 : PHASE==1?64 : PHASE==2?768 : PHASE==3?512 : 256;
  constexpr int NS1 = K1 / 64;          // BK=64 phases
  constexpr int N2  = (PHASE==4) ? 128 : 256;
  constexpr int NF2 = N2 / 128;

  // LDS layout (38,912 B):
  //  [0, 24576)      At 3-buf (stage-1 only; dead after final stage-1 barrier)
  //  [0, 33792)      Ht[64][264] ushort — OVERLAYS At (born after stage 1)
  //  [33792, 35840)  ps[8][64] f32
  //  [35840, 37888)  ps2[8][64] f32
  //  [37888, 38144)  rs_mu[64]
  //  [38144, 38400)  rs_rs[64]
  //  [38400, 38912)  lidx[128] int
  __shared__ __align__(16) char smem[38912];
  auto Ht  = (unsigned short (*)[264])(smem);
  float* ps    = (float*)(smem + 33792);
  float* ps2   = (float*)(smem + 35840);
  float* rs_mu = (float*)(smem + 37888);
  float* rs_rs = (float*)(smem + 38144);
  int*   lidx  = (int*)(smem + 38400);

  const int tid  = threadIdx.x;
  const int wid  = tid >> 6;
  const int lane = tid & 63;
  const int r0   = blockIdx.x * 64;
  const int M    = A.M;

  if constexpr (PHASE == 2) {
    if (tid < 64) {
      int e = r0 + tid; if (e > M - 1) e = M - 1;
      int v = A.snd[e]; v = v < 0 ? 0 : (v > NN - 1 ? NN - 1 : v);
      lidx[tid] = v;
    } else if (tid < 128) {
      int e = r0 + tid - 64; if (e > M - 1) e = M - 1;
      int v = A.rcv[e]; v = v < 0 ? 0 : (v > NN - 1 ? NN - 1 : v);
      lidx[tid] = v;                      // lidx[64..127] = receivers
    }
  }
  __syncthreads();

  const int mrow  = lane & 15;
  const int rbase = (lane >> 4) * 4;
  const int swz   = mrow & 7;            // row-XOR for A-frag reads

  f32x4 zero4 = {0.f, 0.f, 0.f, 0.f};
  f32x4 acc1[4][2];
  #pragma unroll
  for (int m = 0; m < 4; ++m) { acc1[m][0] = zero4; acc1[m][1] = zero4; }

  // ---- stage 1: A @ W1 ----
  if constexpr (PHASE <= 1) {
    // simple path: reg-staged fp32->bf16 with swizzled writes, __syncthreads
    auto stage = [&](int ks, int b) {
      int r = tid >> 3;
      int c = (tid & 7) ^ (r & 7);
      int row = r0 + r; if (row > M - 1) row = M - 1;
      u16x8 w;
      if constexpr (PHASE == 0) {
        const float* s = A.Xf + (size_t)row * 128 + ks * 64 + c * 8;
        float4 f0 = *(const float4*)s;
        float4 f1 = *(const float4*)(s + 4);
        w[0]=f2bf(f0.x); w[1]=f2bf(f0.y); w[2]=f2bf(f0.z); w[3]=f2bf(f0.w);
        w[4]=f2bf(f1.x); w[5]=f2bf(f1.y); w[6]=f2bf(f1.z); w[7]=f2bf(f1.w);
      } else {
        w = (u16x8){0,0,0,0,0,0,0,0};
        if (c == 0) {
          float4 f = *(const float4*)(A.Xf + (size_t)row * 4);
          w[0]=f2bf(f.x); w[1]=f2bf(f.y); w[2]=f2bf(f.z); w[3]=f2bf(f.w);
        }
      }
      *(u16x8*)(smem + b * 8192 + (tid >> 3) * 128 + (tid & 7) * 16) = w;
    };
    stage(0, 0);
    __syncthreads();
    #pragma unroll
    for (int ks = 0; ks < NS1; ++ks) {
      if (ks + 1 < NS1) stage(ks + 1, (ks + 1) & 1);
      const char* buf = smem + (ks & 1) * 8192;
      #pragma unroll
      for (int kk = 0; kk < 2; ++kk) {
        int ch = (kk * 4 + (lane >> 4)) ^ swz;
        const char* p0 = buf + mrow * 128 + ch * 16;
        bf16x8 a0 = *(const bf16x8*)(p0);
        bf16x8 a1 = *(const bf16x8*)(p0 + 16 * 128);
        bf16x8 a2 = *(const bf16x8*)(p0 + 32 * 128);
        bf16x8 a3 = *(const bf16x8*)(p0 + 48 * 128);
        const unsigned short* wb = A.W1p + ((size_t)((2 * ks + kk) * 16 + wid * 2) * 64 + lane) * 8;
        bf16x8 b0 = *(const bf16x8*)(wb);
        bf16x8 b1 = *(const bf16x8*)(wb + 512);
        acc1[0][0] = __builtin_amdgcn_mfma_f32_16x16x32_bf16(a0, b0, acc1[0][0], 0, 0, 0);
        acc1[0][1] = __builtin_amdgcn_mfma_f32_16x16x32_bf16(a0, b1, acc1[0][1], 0, 0, 0);
        acc1[1][0] = __builtin_amdgcn_mfma_f32_16x16x32_bf16(a1, b0, acc1[1][0], 0, 0, 0);
        acc1[1][1] = __builtin_amdgcn_mfma_f32_16x16x32_bf16(a1, b1, acc1[1][1], 0, 0, 0);
        acc1[2][0] = __builtin_amdgcn_mfma_f32_16x16x32_bf16(a2, b0, acc1[2][0], 0, 0, 0);
        acc1[2][1] = __builtin_amdgcn_mfma_f32_16x16x32_bf16(a2, b1, acc1[2][1], 0, 0, 0);
        acc1[3][0] = __builtin_amdgcn_mfma_f32_16x16x32_bf16(a3, b0, acc1[3][0], 0, 0, 0);
        acc1[3][1] = __builtin_amdgcn_mfma_f32_16x16x32_bf16(a3, b1, acc1[3][1], 0, 0, 0);
      }
      __syncthreads();
    }
  } else {
    // pipelined path: gld_lds prefetch depth 3 (triple buffer, mod-3),
    // counted vmcnt (steady-state 2), raw barriers, reg-dbuf W1 fragments.
    int r = tid >> 3;
    int cs = ((tid & 7) ^ (r & 7)) * 8;      // swizzled source elem offset
    int row = r0 + r; if (row > M - 1) row = M - 1;
    const unsigned short *s0 = nullptr, *s1 = nullptr, *s2 = nullptr;
    if constexpr (PHASE == 2) {
      s0 = A.edgeB + (size_t)row * 256 + cs;
      s1 = A.nodeB + (size_t)lidx[r] * 256 + cs;
      s2 = A.nodeB + (size_t)lidx[64 + r] * 256 + cs;
    } else if constexpr (PHASE == 3) {
      s0 = A.nodeB + (size_t)row * 256 + cs;
      s1 = A.aggB + (size_t)row * 256 + cs;
    } else {
      s0 = A.nodeB + (size_t)row * 256 + cs;
    }
    auto issue = [&](int ks) {
      const unsigned short* src;
      if constexpr (PHASE == 2)
        src = ks < 4 ? s0 + ks * 64 : (ks < 8 ? s1 + (ks - 4) * 64 : s2 + (ks - 8) * 64);
      else if constexpr (PHASE == 3)
        src = ks < 4 ? s0 + ks * 64 : s1 + (ks - 4) * 64;
      else
        src = s0 + ks * 64;
      gld_lds16(src, smem + (ks % 3) * 8192 + wid * 1024);
    };
    const unsigned short* w1base = A.W1p + ((size_t)(wid * 2) * 64 + lane) * 8;
    auto load_b = [&](int ks, bf16x8* bk0, bf16x8* bk1) {
      const unsigned short* wb0 = w1base + (size_t)(2 * ks) * 16 * 512;
      const unsigned short* wb1 = w1base + (size_t)(2 * ks + 1) * 16 * 512;
      bk0[0] = *(const bf16x8*)(wb0); bk0[1] = *(const bf16x8*)(wb0 + 512);
      bk1[0] = *(const bf16x8*)(wb1); bk1[1] = *(const bf16x8*)(wb1 + 512);
    };

    issue(0);
    issue(1);
    issue(2);
    bf16x8 c0[2], c1[2], n0[2], n1[2];
    load_b(0, c0, c1);
    #pragma unroll
    for (int ks = 0; ks < NS1; ++ks) {
      int rem = NS1 - 1 - ks;               // tiles still outstanding beyond ks
      if (rem >= 2)      asm volatile("s_waitcnt vmcnt(2)" ::: "memory");
      else if (rem == 1) asm volatile("s_waitcnt vmcnt(1)" ::: "memory");
      else               asm volatile("s_waitcnt vmcnt(0)" ::: "memory");
      __builtin_amdgcn_sched_barrier(0);
      __builtin_amdgcn_s_barrier();
      __builtin_amdgcn_sched_barrier(0);
      if (ks + 1 < NS1) load_b(ks + 1, n0, n1);   // next phase's W1 frags
      const char* buf = smem + (ks % 3) * 8192;
      #pragma unroll
      for (int kk = 0; kk < 2; ++kk) {
        int ch = (kk * 4 + (lane >> 4)) ^ swz;
        const char* p0 = buf + mrow * 128 + ch * 16;
        bf16x8 a0 = *(const bf16x8*)(p0);
        bf16x8 a1 = *(const bf16x8*)(p0 + 16 * 128);
        bf16x8 a2 = *(const bf16x8*)(p0 + 32 * 128);
        bf16x8 a3 = *(const bf16x8*)(p0 + 48 * 128);
        bf16x8 b0 = kk ? c1[0] : c0[0];
        bf16x8 b1 = kk ? c1[1] : c0[1];
        acc1[0][0] = __builtin_amdgcn_mfma_f32_16x16x32_bf16(a0, b0, acc1[0][0], 0, 0, 0);
        acc1[0][1] = __builtin_amdgcn_mfma_f32_16x16x32_bf16(a0, b1, acc1[0][1], 0, 0, 0);
        acc1[1][0] = __builtin_amdgcn_mfma_f32_16x16x32_bf16(a1, b0, acc1[1][0], 0, 0, 0);
        acc1[1][1] = __builtin_amdgcn_mfma_f32_16x16x32_bf16(a1, b1, acc1[1][1], 0, 0, 0);
        acc1[2][0] = __builtin_amdgcn_mfma_f32_16x16x32_bf16(a2, b0, acc1[2][0], 0, 0, 0);
        acc1[2][1] = __builtin_amdgcn_mfma_f32_16x16x32_bf16(a2, b1, acc1[2][1], 0, 0, 0);
        acc1[3][0] = __builtin_amdgcn_mfma_f32_16x16x32_bf16(a3, b0, acc1[3][0], 0, 0, 0);
        acc1[3][1] = __builtin_amdgcn_mfma_f32_16x16x32_bf16(a3, b1, acc1[3][1], 0, 0, 0);
      }
      __builtin_amdgcn_sched_barrier(0);
      __builtin_amdgcn_s_barrier();
      __builtin_amdgcn_sched_barrier(0);
      if (ks + 3 < NS1) issue(ks + 3);
      c0[0] = n0[0]; c0[1] = n0[1]; c1[0] = n1[0]; c1[1] = n1[1];
    }
  }

  // ---- bias + swish -> Ht (overlays dead At; all At reads retired by the
  // final stage-1 barrier) ----
  #pragma unroll
  for (int nf = 0; nf < 2; ++nf) {
    int c = wid * 32 + nf * 16 + mrow;
    float bb = A.b1[c];
    #pragma unroll
    for (int m = 0; m < 4; ++m)
      #pragma unroll
      for (int j = 0; j < 4; ++j) {
        float x = acc1[m][nf][j] + bb;
        float h = x * (1.f / (1.f + __expf(-x)));
        Ht[m * 16 + rbase + j][c] = f2bf(h);
      }
  }
  __syncthreads();

  // ---- stage 2: Ht @ W2 (K=256, 8 k-steps, no barriers) ----
  f32x4 acc2[4][NF2];
  #pragma unroll
  for (int m = 0; m < 4; ++m)
    #pragma unroll
    for (int nf = 0; nf < NF2; ++nf) acc2[m][nf] = zero4;

  const int kof = (lane >> 4) * 8;
  #pragma unroll
  for (int ks = 0; ks < 8; ++ks) {
    bf16x8 a[4], b[NF2];
    #pragma unroll
    for (int m = 0; m < 4; ++m)
      a[m] = *(const bf16x8*)&Ht[m * 16 + mrow][ks * 32 + kof];
    #pragma unroll
    for (int nf = 0; nf < NF2; ++nf)
      b[nf] = *(const bf16x8*)(A.W2p + ((size_t)(ks * (N2 / 16) + wid * NF2 + nf) * 64 + lane) * 8);
    #pragma unroll
    for (int m = 0; m < 4; ++m)
      #pragma unroll
      for (int nf = 0; nf < NF2; ++nf)
        acc2[m][nf] = __builtin_amdgcn_mfma_f32_16x16x32_bf16(a[m], b[nf], acc2[m][nf], 0, 0, 0);
  }

  // ---- epilogue ----
  if constexpr (PHASE == 4) {
    int c = wid * 16 + mrow;
    float bb = A.b2[c];
    #pragma unroll
    for (int m = 0; m < 4; ++m)
      #pragma unroll
      for (int j = 0; j < 4; ++j) {
        int rg = r0 + m * 16 + rbase + j;
        if (rg < M) A.outF[(size_t)rg * 128 + c] = acc2[m][0][j] + bb;   // fp32 out
      }
  } else {
    const int cc0 = wid * 32 + mrow;
    const int cc1 = cc0 + 16;
    const float bb0 = A.b2[cc0];
    const float bb1 = A.b2[cc1];
    // LN stats: 16-lane shfl reduce -> per-wave partials (own region) -> combine.
    #pragma unroll
    for (int m = 0; m < 4; ++m)
      #pragma unroll
      for (int j = 0; j < 4; ++j) {
        acc2[m][0][j] += bb0;
        acc2[m][1][j] += bb1;
        float t  = acc2[m][0][j] + acc2[m][1][j];
        float t2 = acc2[m][0][j] * acc2[m][0][j] + acc2[m][1][j] * acc2[m][1][j];
        #pragma unroll
        for (int mk = 1; mk < 16; mk <<= 1) {
          t  += __shfl_xor(t, mk);
          t2 += __shfl_xor(t2, mk);
        }
        if (mrow == 0) {
          int row = m * 16 + rbase + j;
          ps [wid * 64 + row] = t;
          ps2[wid * 64 + row] = t2;
        }
      }
    __syncthreads();
    if (tid < 64) {
      float s = 0.f, q = 0.f;
      #pragma unroll
      for (int w = 0; w < 8; ++w) { s += ps[w * 64 + tid]; q += ps2[w * 64 + tid]; }
      float mu = s * (1.0f / 256.0f);
      float va = fmaxf(q * (1.0f / 256.0f) - mu * mu, 0.f);
      rs_mu[tid] = mu;
      rs_rs[tid] = rsqrtf(va + 1e-5f);
    }
    __syncthreads();
    const float ls0 = A.lns[cc0], lo0 = A.lno[cc0];
    const float ls1 = A.lns[cc1], lo1 = A.lno[cc1];
    #pragma unroll
    for (int m = 0; m < 4; ++m)
      #pragma unroll
      for (int j = 0; j < 4; ++j) {
        int row = m * 16 + rbase + j;
        int rg = r0 + row;
        if (rg >= M) continue;
        float mu = rs_mu[row], rstd = rs_rs[row];
        float y0 = (acc2[m][0][j] - mu) * rstd * ls0 + lo0;
        float y1 = (acc2[m][1][j] - mu) * rstd * ls1 + lo1;
        size_t base = (size_t)rg * 256;
        if constexpr (PHASE == 0) {
          A.nodeB[base + cc0] = f2bf(y0);
          A.nodeB[base + cc1] = f2bf(y1);
        } else if constexpr (PHASE == 1) {
          A.edgeB[base + cc0] = f2bf(y0);
          A.edgeB[base + cc1] = f2bf(y1);
        } else if constexpr (PHASE == 2) {
          A.edgeB[base + cc0] = f2bf(bf2f(A.edgeB[base + cc0]) + y0);
          A.edgeB[base + cc1] = f2bf(bf2f(A.edgeB[base + cc1]) + y1);
        } else {  // PHASE 3: node residual
          A.nodeB[base + cc0] = f2bf(bf2f(A.nodeB[base + cc0]) + y0);
          A.nodeB[base + cc1] = f2bf(bf2f(A.nodeB[base + cc1]) + y1);
        }
      }
  }
}

extern "C" void kernel_launch(void* const* d_in, const int* in_sizes, int n_in,
                              void* d_out, int out_size, void* d_ws, size_t ws_size,
                              hipStream_t stream) {
  (void)in_sizes; (void)n_in; (void)out_size; (void)ws_size;
  const float* x_node = (const float*)d_in[0];
  const float* x_edge = (const float*)d_in[1];
  const int* snd = (const int*)d_in[2];
  const int* rcv = (const int*)d_in[3];
  const float* en_w1 = (const float*)d_in[4];
  const float* en_b1 = (const float*)d_in[5];
  const float* en_w2 = (const float*)d_in[6];
  const float* en_b2 = (const float*)d_in[7];
  const float* en_ls = (const float*)d_in[8];
  const float* en_lo = (const float*)d_in[9];
  const float* ee_w1 = (const float*)d_in[10];
  const float* ee_b1 = (const float*)d_in[11];
  const float* ee_w2 = (const float*)d_in[12];
  const float* ee_b2 = (const float*)d_in[13];
  const float* ee_ls = (const float*)d_in[14];
  const float* ee_lo = (const float*)d_in[15];
  const float* pe_w1 = (const float*)d_in[16];
  const float* pe_b1 = (const float*)d_in[17];
  const float* pe_w2 = (const float*)d_in[18];
  const float* pe_b2 = (const float*)d_in[19];
  const float* pe_ls = (const float*)d_in[20];
  const float* pe_lo = (const float*)d_in[21];
  const float* pn_w1 = (const float*)d_in[22];
  const float* pn_b1 = (const float*)d_in[23];
  const float* pn_w2 = (const float*)d_in[24];
  const float* pn_b2 = (const float*)d_in[25];
  const float* pn_ls = (const float*)d_in[26];
  const float* pn_lo = (const float*)d_in[27];
  const float* dc_w1 = (const float*)d_in[28];
  const float* dc_b1 = (const float*)d_in[29];
  const float* dc_w2 = (const float*)d_in[30];
  const float* dc_b2 = (const float*)d_in[31];

  // ---- workspace: exactly 256,000,000 bytes ----
  char* ws = (char*)d_ws;
  unsigned short* edgeB = (unsigned short*)(ws);                  // 153,600,000 B
  unsigned short* nodeB = (unsigned short*)(ws + 153600000LL);    //  51,200,000 B
  unsigned short* aggB  = (unsigned short*)(ws + 204800000LL);    //  51,200,000 B

  // ---- packed bf16 weights + CSR scratch in d_out (51.2MB fp32 buffer) ----
  unsigned short* wpck = (unsigned short*)d_out;
  size_t o = 0;
  auto nxt = [&](size_t n) { unsigned short* p = wpck + o; o += n; return p; };
  unsigned short* p_en_w1 = nxt(128 * 256);
  unsigned short* p_en_w2 = nxt(256 * 256);
  unsigned short* p_ee_w1 = nxt(64 * 256);                 // Kpad 64
  unsigned short* p_ee_w2 = nxt(256 * 256);
  unsigned short* p_pe_w1 = nxt((size_t)6 * 768 * 256);
  unsigned short* p_pe_w2 = nxt((size_t)6 * 256 * 256);
  unsigned short* p_pn_w1 = nxt((size_t)6 * 512 * 256);
  unsigned short* p_pn_w2 = nxt((size_t)6 * 256 * 256);
  unsigned short* p_dc_w1 = nxt(256 * 256);     // dc block contiguous
  unsigned short* p_dc_w2 = nxt(256 * 128);
  const size_t DC_BYTES = (256 * 256 + 256 * 128) * 2;  // 196,608

  char* outc = (char*)d_out;
  int* cnt  = (int*)(outc + 6062080);    //   400,000 B
  int* cnt2 = (int*)(outc + 6462080);    //   400,000 B
  int* off  = (int*)(outc + 6862080);    //   400,004 B
  int* eidx = (int*)(outc + 7262096);    // 1,200,000 B (ends 8,462,096 < 51.2MB)

  dim3 B(512);
  pack_w<<<dim3(4 * 16, 1), B, 0, stream>>>(en_w1, p_en_w1, 128, 128, 256);
  pack_w<<<dim3(8 * 16, 1), B, 0, stream>>>(en_w2, p_en_w2, 256, 256, 256);
  pack_w<<<dim3(2 * 16, 1), B, 0, stream>>>(ee_w1, p_ee_w1, 4, 64, 256);
  pack_w<<<dim3(8 * 16, 1), B, 0, stream>>>(ee_w2, p_ee_w2, 256, 256, 256);
  pack_w<<<dim3(24 * 16, 6), B, 0, stream>>>(pe_w1, p_pe_w1, 768, 768, 256);
  pack_w<<<dim3(8 * 16, 6), B, 0, stream>>>(pe_w2, p_pe_w2, 256, 256, 256);
  pack_w<<<dim3(16 * 16, 6), B, 0, stream>>>(pn_w1, p_pn_w1, 512, 512, 256);
  pack_w<<<dim3(8 * 16, 6), B, 0, stream>>>(pn_w2, p_pn_w2, 256, 256, 256);
  pack_w<<<dim3(8 * 16, 1), B, 0, stream>>>(dc_w1, p_dc_w1, 256, 256, 256);
  pack_w<<<dim3(8 * 8, 1), B, 0, stream>>>(dc_w2, p_dc_w2, 256, 256, 128);

  // ---- CSR build (ints only; rebuilt every launch) ----
  zero_ws<<<dim3(196), dim3(256), 0, stream>>>((uint4*)cnt, 800000 / 16);
  hist_k<<<dim3(1172), dim3(256), 0, stream>>>(rcv, cnt);
  scan_k<<<dim3(1), dim3(1024), 0, stream>>>(cnt, off);
  fill_k<<<dim3(1172), dim3(256), 0, stream>>>(rcv, off, cnt2, eidx);

  dim3 GN(1563), GE(4688);

  { // encoder: nodes
    KArgs a{}; a.Xf = x_node; a.W1p = p_en_w1; a.W2p = p_en_w2;
    a.b1 = en_b1; a.b2 = en_b2; a.lns = en_ls; a.lno = en_lo;
    a.nodeB = nodeB; a.M = NN;
    gnn_kernel<0><<<GN, B, 0, stream>>>(a);
  }
  { // encoder: edges
    KArgs a{}; a.Xf = x_edge; a.W1p = p_ee_w1; a.W2p = p_ee_w2;
    a.b1 = ee_b1; a.b2 = ee_b2; a.lns = ee_ls; a.lno = ee_lo;
    a.edgeB = edgeB; a.M = NE;
    gnn_kernel<1><<<GE, B, 0, stream>>>(a);
  }
  for (int s = 0; s < 6; ++s) {
    { // edge update (in-place residual)
      KArgs a{}; a.snd = snd; a.rcv = rcv;
      a.nodeB = nodeB; a.edgeB = edgeB;
      a.W1p = p_pe_w1 + (size_t)s * 768 * 256;
      a.W2p = p_pe_w2 + (size_t)s * 256 * 256;
      a.b1 = pe_b1 + s * 256; a.b2 = pe_b2 + s * 256;
      a.lns = pe_ls + s * 256; a.lno = pe_lo + s * 256;
      a.M = NE;
      gnn_kernel<2><<<GE, B, 0, stream>>>(a);
    }
    // aggregate: CSR gather, fp32 accumulate
    agg_k<<<dim3(12500), dim3(256), 0, stream>>>(edgeB, off, eidx, aggB);
    { // node update (in-place residual)
      KArgs a{}; a.nodeB = nodeB; a.aggB = aggB;
      a.W1p = p_pn_w1 + (size_t)s * 512 * 256;
      a.W2p = p_pn_w2 + (size_t)s * 256 * 256;
      a.b1 = pn_b1 + s * 256; a.b2 = pn_b2 + s * 256;
      a.lns = pn_ls + s * 256; a.lno = pn_lo + s * 256;
      a.M = NN;
      gnn_kernel<3><<<GN, B, 0, stream>>>(a);
    }
  }
  // move decoder packed weights out of d_out (agg region is dead now)
  hipMemcpyAsync((void*)aggB, p_dc_w1, DC_BYTES, hipMemcpyDeviceToDevice, stream);
  { // decoder (overwrites all of d_out with fp32 output)
    KArgs a{}; a.nodeB = nodeB;
    a.W1p = (const unsigned short*)aggB;
    a.W2p = (const unsigned short*)aggB + 256 * 256;
    a.b1 = dc_b1; a.b2 = dc_b2;
    a.outF = (float*)d_out; a.M = NN;
    gnn_kernel<4><<<GN, B, 0, stream>>>(a);
  }
}

// Round 18
// 2707.499 us; speedup vs baseline: 1.1094x; 1.1094x over previous
//
#include <hip/hip_runtime.h>
#include <hip/hip_bf16.h>

// GraphCast-style GNN: encode -> 6x InteractionNetwork -> decode.
// INPUTS fp32, OUTPUT fp32. Internal state bf16.
// State in d_ws, EXACTLY 256,000,000 B: [edge 153.6MB][node 51.2MB][agg 51.2MB].
// Packed bf16 weights + CSR in d_out scratch; decoder overwrites d_out last.
// R18 == R12 (best measured: 2718 us): BK=64, gld_lds(16B) staging, XOR-swizzled
// A-tile, counted-vmcnt raw-barrier pipeline (prefetch dist 2), reg-dbuf W1.

#define NN 100000
#define NE 300000

typedef __attribute__((ext_vector_type(8))) short bf16x8;
typedef __attribute__((ext_vector_type(8))) unsigned short u16x8;
typedef __attribute__((ext_vector_type(4))) float f32x4;

typedef const __attribute__((address_space(1))) void cg1_t;
typedef __attribute__((address_space(3))) void l3_t;
static __device__ __forceinline__ void gld_lds16(const void* g, void* l) {
  __builtin_amdgcn_global_load_lds((cg1_t*)g, (l3_t*)l, 16, 0, 0);
}

static __device__ __forceinline__ unsigned short f2bf(float f) {
  union { float f; unsigned u; } v; v.f = f;
  unsigned r = v.u + 0x7FFFu + ((v.u >> 16) & 1u);   // RNE
  unsigned short h = (unsigned short)(r >> 16);
  if ((h & 0x7F80u) == 0x7F80u) h = 0;               // safety scrub
  return h;
}
static __device__ __forceinline__ float bf2f(unsigned short h) {
  union { unsigned u; float f; } v; v.u = ((unsigned)h) << 16;
  return v.f;
}

struct KArgs {
  const float* Xf;             // raw fp32 input (encoder phases)
  unsigned short* nodeB;       // node latent bf16
  unsigned short* edgeB;       // edge latent bf16
  const unsigned short* aggB;  // agg bf16 (node step reads)
  const int* snd;
  const int* rcv;
  const unsigned short* W1p;   // packed W1 (bf16, MFMA frag order)
  const unsigned short* W2p;   // packed W2
  const float* b1;
  const float* b2;
  const float* lns;
  const float* lno;
  float* outF;                 // decoder output (d_out, fp32)
  int M;
};

// Pack fp32 W [Ksrc x N] (zero-pad K to Kpad) into bf16 frag order:
// frag fi=kb*(N/16)+nb; elem (lane,j) = W[kb*32+(lane>>4)*8+j][nb*16+(lane&15)].
__global__ void pack_w(const float* __restrict__ src,
                       unsigned short* __restrict__ dst,
                       int Ksrc, int Kpad, int N) {
  src += (size_t)blockIdx.y * Ksrc * N;
  dst += (size_t)blockIdx.y * Kpad * N;
  int fi = blockIdx.x;
  int nfr = N >> 4;
  int nb = fi % nfr, kb = fi / nfr;
  int t = threadIdx.x;               // 512
  int lane = t >> 3, j = t & 7;
  int k = kb * 32 + ((lane >> 4) * 8) + j;
  int col = nb * 16 + (lane & 15);
  unsigned short v = (k < Ksrc) ? f2bf(src[(size_t)k * N + col]) : (unsigned short)0;
  dst[(size_t)fi * 512 + t] = v;
}

__global__ void zero_ws(uint4* __restrict__ p, int n16) {
  uint4 z = {0u, 0u, 0u, 0u};
  for (int i = blockIdx.x * blockDim.x + threadIdx.x; i < n16;
       i += gridDim.x * blockDim.x)
    p[i] = z;
}

__global__ void hist_k(const int* __restrict__ rcv, int* __restrict__ cnt) {
  int e = blockIdx.x * blockDim.x + threadIdx.x;
  if (e < NE) {
    int r = rcv[e]; r = r < 0 ? 0 : (r > NN - 1 ? NN - 1 : r);
    atomicAdd(&cnt[r], 1);
  }
}

__global__ __launch_bounds__(1024)
void scan_k(const int* __restrict__ cnt, int* __restrict__ off) {
  __shared__ int wsum[16];
  __shared__ int carry_s, tot_s;
  int t = threadIdx.x, lane = t & 63, w = t >> 6;
  if (t == 0) carry_s = 0;
  __syncthreads();
  for (int base = 0; base < NN; base += 1024) {
    int i = base + t;
    int v = (i < NN) ? cnt[i] : 0;
    int incl = v;
    #pragma unroll
    for (int d = 1; d < 64; d <<= 1) {
      int u = __shfl_up(incl, d);
      if (lane >= d) incl += u;
    }
    if (lane == 63) wsum[w] = incl;
    int c0 = carry_s;
    __syncthreads();
    if (t < 16) {
      int s = wsum[t];
      int isc = s;
      #pragma unroll
      for (int d = 1; d < 16; d <<= 1) {
        int u = __shfl_up(isc, d);
        if (t >= d) isc += u;
      }
      wsum[t] = isc - s;               // exclusive wave offset
    }
    __syncthreads();
    int excl = c0 + wsum[w] + incl - v;
    if (i < NN) off[i] = excl;
    if (t == 1023) tot_s = wsum[15] + incl;
    __syncthreads();
    if (t == 0) carry_s += tot_s;
    __syncthreads();
  }
  if (t == 0) off[NN] = carry_s;
}

__global__ void fill_k(const int* __restrict__ rcv, const int* __restrict__ off,
                       int* __restrict__ cnt2, int* __restrict__ eidx) {
  int e = blockIdx.x * blockDim.x + threadIdx.x;
  if (e < NE) {
    int r = rcv[e]; r = r < 0 ? 0 : (r > NN - 1 ? NN - 1 : r);
    int p = off[r] + atomicAdd(&cnt2[r], 1);
    if (p >= 0 && p < NE) eidx[p] = e;
  }
}

// agg[n][t] = sum over incoming edges of edge[e][t]; fp32 accumulate.
__global__ __launch_bounds__(256)
void agg_k(const unsigned short* __restrict__ edge, const int* __restrict__ off,
           const int* __restrict__ eidx, unsigned short* __restrict__ agg) {
  int t = threadIdx.x;
  int n0 = blockIdx.x * 8;
  #pragma unroll 1
  for (int u = 0; u < 8; ++u) {
    int n = n0 + u;
    if (n >= NN) return;
    int s = off[n], e = off[n + 1];
    if (s < 0) s = 0;
    if (e > NE) e = NE;
    float acc = 0.f;
    for (int i = s; i < e; ++i) {
      int eid = eidx[i];
      eid = eid < 0 ? 0 : (eid > NE - 1 ? NE - 1 : eid);
      acc += bf2f(edge[(size_t)eid * 256 + t]);
    }
    agg[(size_t)n * 256 + t] = f2bf(acc);
  }
}

// PHASE: 0 enc_node, 1 enc_edge, 2 edge_step, 3 node_step, 4 decoder.
// 64-row tile, BK=64 phases, 8 waves. A-tile: linear 128B rows, XOR-swizzled
// 16B chunks: chunk c of row r lives at slot (c ^ (r&7)).
template<int PHASE>
__global__ __launch_bounds__(512)
void gnn_kernel(KArgs A) {
  constexpr int K1  = PHASE==0?128 : PHASE==1?64 : PHASE==2?768 : PHASE==3?512 : 256;
  constexpr int NS1 = K1 / 64;          // BK=64 phases
  constexpr int N2  = (PHASE==4) ? 128 : 256;
  constexpr int NF2 = N2 / 128;

  // LDS layout (50,688 B -> 3 blocks/CU):
  //  [0, 16384)      At dbuf: buf b at b*8192, row r at r*128 (swizzled chunks)
  //  [16384, 50176)  Ht[64][264] ushort
  //  [50176, 50688)  lidx[128] int
  //  overlay on At (dead after stage 1): ps/ps2/mu/rs
  __shared__ __align__(16) char smem[50688];
  auto Ht  = (unsigned short (*)[264])(smem + 16384);
  int*   lidx = (int*)(smem + 50176);
  float* ps    = (float*)smem;
  float* ps2   = (float*)(smem + 2048);
  float* rs_mu = (float*)(smem + 4096);
  float* rs_rs = (float*)(smem + 4352);

  const int tid  = threadIdx.x;
  const int wid  = tid >> 6;
  const int lane = tid & 63;
  const int r0   = blockIdx.x * 64;
  const int M    = A.M;

  if constexpr (PHASE == 2) {
    if (tid < 64) {
      int e = r0 + tid; if (e > M - 1) e = M - 1;
      int v = A.snd[e]; v = v < 0 ? 0 : (v > NN - 1 ? NN - 1 : v);
      lidx[tid] = v;
    } else if (tid < 128) {
      int e = r0 + tid - 64; if (e > M - 1) e = M - 1;
      int v = A.rcv[e]; v = v < 0 ? 0 : (v > NN - 1 ? NN - 1 : v);
      lidx[tid] = v;                      // lidx[64..127] = receivers
    }
  }
  __syncthreads();

  const int mrow  = lane & 15;
  const int rbase = (lane >> 4) * 4;
  const int swz   = mrow & 7;            // row-XOR for A-frag reads

  f32x4 zero4 = {0.f, 0.f, 0.f, 0.f};
  f32x4 acc1[4][2];
  #pragma unroll
  for (int m = 0; m < 4; ++m) { acc1[m][0] = zero4; acc1[m][1] = zero4; }

  // ---- stage 1: A @ W1 ----
  if constexpr (PHASE <= 1) {
    // simple path: reg-staged fp32->bf16 with swizzled writes, __syncthreads
    auto stage = [&](int ks, int b) {
      int r = tid >> 3;
      int c = (tid & 7) ^ (r & 7);
      int row = r0 + r; if (row > M - 1) row = M - 1;
      u16x8 w;
      if constexpr (PHASE == 0) {
        const float* s = A.Xf + (size_t)row * 128 + ks * 64 + c * 8;
        float4 f0 = *(const float4*)s;
        float4 f1 = *(const float4*)(s + 4);
        w[0]=f2bf(f0.x); w[1]=f2bf(f0.y); w[2]=f2bf(f0.z); w[3]=f2bf(f0.w);
        w[4]=f2bf(f1.x); w[5]=f2bf(f1.y); w[6]=f2bf(f1.z); w[7]=f2bf(f1.w);
      } else {
        w = (u16x8){0,0,0,0,0,0,0,0};
        if (c == 0) {
          float4 f = *(const float4*)(A.Xf + (size_t)row * 4);
          w[0]=f2bf(f.x); w[1]=f2bf(f.y); w[2]=f2bf(f.z); w[3]=f2bf(f.w);
        }
      }
      *(u16x8*)(smem + b * 8192 + (tid >> 3) * 128 + (tid & 7) * 16) = w;
    };
    stage(0, 0);
    __syncthreads();
    #pragma unroll
    for (int ks = 0; ks < NS1; ++ks) {
      if (ks + 1 < NS1) stage(ks + 1, (ks + 1) & 1);
      const char* buf = smem + (ks & 1) * 8192;
      #pragma unroll
      for (int kk = 0; kk < 2; ++kk) {
        int ch = (kk * 4 + (lane >> 4)) ^ swz;
        const char* p0 = buf + mrow * 128 + ch * 16;
        bf16x8 a0 = *(const bf16x8*)(p0);
        bf16x8 a1 = *(const bf16x8*)(p0 + 16 * 128);
        bf16x8 a2 = *(const bf16x8*)(p0 + 32 * 128);
        bf16x8 a3 = *(const bf16x8*)(p0 + 48 * 128);
        const unsigned short* wb = A.W1p + ((size_t)((2 * ks + kk) * 16 + wid * 2) * 64 + lane) * 8;
        bf16x8 b0 = *(const bf16x8*)(wb);
        bf16x8 b1 = *(const bf16x8*)(wb + 512);
        acc1[0][0] = __builtin_amdgcn_mfma_f32_16x16x32_bf16(a0, b0, acc1[0][0], 0, 0, 0);
        acc1[0][1] = __builtin_amdgcn_mfma_f32_16x16x32_bf16(a0, b1, acc1[0][1], 0, 0, 0);
        acc1[1][0] = __builtin_amdgcn_mfma_f32_16x16x32_bf16(a1, b0, acc1[1][0], 0, 0, 0);
        acc1[1][1] = __builtin_amdgcn_mfma_f32_16x16x32_bf16(a1, b1, acc1[1][1], 0, 0, 0);
        acc1[2][0] = __builtin_amdgcn_mfma_f32_16x16x32_bf16(a2, b0, acc1[2][0], 0, 0, 0);
        acc1[2][1] = __builtin_amdgcn_mfma_f32_16x16x32_bf16(a2, b1, acc1[2][1], 0, 0, 0);
        acc1[3][0] = __builtin_amdgcn_mfma_f32_16x16x32_bf16(a3, b0, acc1[3][0], 0, 0, 0);
        acc1[3][1] = __builtin_amdgcn_mfma_f32_16x16x32_bf16(a3, b1, acc1[3][1], 0, 0, 0);
      }
      __syncthreads();
    }
  } else {
    // pipelined path: gld_lds prefetch dist 2, counted vmcnt, raw barriers,
    // register double-buffered W1 fragments.
    int r = tid >> 3;
    int cs = ((tid & 7) ^ (r & 7)) * 8;      // swizzled source elem offset
    int row = r0 + r; if (row > M - 1) row = M - 1;
    const unsigned short *s0 = nullptr, *s1 = nullptr, *s2 = nullptr;
    if constexpr (PHASE == 2) {
      s0 = A.edgeB + (size_t)row * 256 + cs;
      s1 = A.nodeB + (size_t)lidx[r] * 256 + cs;
      s2 = A.nodeB + (size_t)lidx[64 + r] * 256 + cs;
    } else if constexpr (PHASE == 3) {
      s0 = A.nodeB + (size_t)row * 256 + cs;
      s1 = A.aggB + (size_t)row * 256 + cs;
    } else {
      s0 = A.nodeB + (size_t)row * 256 + cs;
    }
    auto issue = [&](int ks, int b) {
      const unsigned short* src;
      if constexpr (PHASE == 2)
        src = ks < 4 ? s0 + ks * 64 : (ks < 8 ? s1 + (ks - 4) * 64 : s2 + (ks - 8) * 64);
      else if constexpr (PHASE == 3)
        src = ks < 4 ? s0 + ks * 64 : s1 + (ks - 4) * 64;
      else
        src = s0 + ks * 64;
      gld_lds16(src, smem + b * 8192 + wid * 1024);
    };
    const unsigned short* w1base = A.W1p + ((size_t)(wid * 2) * 64 + lane) * 8;
    auto load_b = [&](int ks, bf16x8* bk0, bf16x8* bk1) {
      const unsigned short* wb0 = w1base + (size_t)(2 * ks) * 16 * 512;
      const unsigned short* wb1 = w1base + (size_t)(2 * ks + 1) * 16 * 512;
      bk0[0] = *(const bf16x8*)(wb0); bk0[1] = *(const bf16x8*)(wb0 + 512);
      bk1[0] = *(const bf16x8*)(wb1); bk1[1] = *(const bf16x8*)(wb1 + 512);
    };

    issue(0, 0);
    issue(1, 1);
    bf16x8 c0[2], c1[2], n0[2], n1[2];
    load_b(0, c0, c1);
    #pragma unroll
    for (int ks = 0; ks < NS1; ++ks) {
      if (ks < NS1 - 1) asm volatile("s_waitcnt vmcnt(1)" ::: "memory");
      else              asm volatile("s_waitcnt vmcnt(0)" ::: "memory");
      __builtin_amdgcn_sched_barrier(0);
      __builtin_amdgcn_s_barrier();
      __builtin_amdgcn_sched_barrier(0);
      if (ks + 1 < NS1) load_b(ks + 1, n0, n1);   // next phase's W1 frags
      const char* buf = smem + (ks & 1) * 8192;
      #pragma unroll
      for (int kk = 0; kk < 2; ++kk) {
        int ch = (kk * 4 + (lane >> 4)) ^ swz;
        const char* p0 = buf + mrow * 128 + ch * 16;
        bf16x8 a0 = *(const bf16x8*)(p0);
        bf16x8 a1 = *(const bf16x8*)(p0 + 16 * 128);
        bf16x8 a2 = *(const bf16x8*)(p0 + 32 * 128);
        bf16x8 a3 = *(const bf16x8*)(p0 + 48 * 128);
        bf16x8 b0 = kk ? c1[0] : c0[0];
        bf16x8 b1 = kk ? c1[1] : c0[1];
        acc1[0][0] = __builtin_amdgcn_mfma_f32_16x16x32_bf16(a0, b0, acc1[0][0], 0, 0, 0);
        acc1[0][1] = __builtin_amdgcn_mfma_f32_16x16x32_bf16(a0, b1, acc1[0][1], 0, 0, 0);
        acc1[1][0] = __builtin_amdgcn_mfma_f32_16x16x32_bf16(a1, b0, acc1[1][0], 0, 0, 0);
        acc1[1][1] = __builtin_amdgcn_mfma_f32_16x16x32_bf16(a1, b1, acc1[1][1], 0, 0, 0);
        acc1[2][0] = __builtin_amdgcn_mfma_f32_16x16x32_bf16(a2, b0, acc1[2][0], 0, 0, 0);
        acc1[2][1] = __builtin_amdgcn_mfma_f32_16x16x32_bf16(a2, b1, acc1[2][1], 0, 0, 0);
        acc1[3][0] = __builtin_amdgcn_mfma_f32_16x16x32_bf16(a3, b0, acc1[3][0], 0, 0, 0);
        acc1[3][1] = __builtin_amdgcn_mfma_f32_16x16x32_bf16(a3, b1, acc1[3][1], 0, 0, 0);
      }
      __builtin_amdgcn_sched_barrier(0);
      __builtin_amdgcn_s_barrier();
      __builtin_amdgcn_sched_barrier(0);
      if (ks + 2 < NS1) issue(ks + 2, ks & 1);
      c0[0] = n0[0]; c0[1] = n0[1]; c1[0] = n1[0]; c1[1] = n1[1];
    }
  }

  // ---- bias + swish -> Ht ----
  #pragma unroll
  for (int nf = 0; nf < 2; ++nf) {
    int c = wid * 32 + nf * 16 + mrow;
    float bb = A.b1[c];
    #pragma unroll
    for (int m = 0; m < 4; ++m)
      #pragma unroll
      for (int j = 0; j < 4; ++j) {
        float x = acc1[m][nf][j] + bb;
        float h = x * (1.f / (1.f + __expf(-x)));
        Ht[m * 16 + rbase + j][c] = f2bf(h);
      }
  }
  __syncthreads();

  // ---- stage 2: Ht @ W2 (K=256, 8 k-steps, no barriers) ----
  f32x4 acc2[4][NF2];
  #pragma unroll
  for (int m = 0; m < 4; ++m)
    #pragma unroll
    for (int nf = 0; nf < NF2; ++nf) acc2[m][nf] = zero4;

  const int kof = (lane >> 4) * 8;
  #pragma unroll
  for (int ks = 0; ks < 8; ++ks) {
    bf16x8 a[4], b[NF2];
    #pragma unroll
    for (int m = 0; m < 4; ++m)
      a[m] = *(const bf16x8*)&Ht[m * 16 + mrow][ks * 32 + kof];
    #pragma unroll
    for (int nf = 0; nf < NF2; ++nf)
      b[nf] = *(const bf16x8*)(A.W2p + ((size_t)(ks * (N2 / 16) + wid * NF2 + nf) * 64 + lane) * 8);
    #pragma unroll
    for (int m = 0; m < 4; ++m)
      #pragma unroll
      for (int nf = 0; nf < NF2; ++nf)
        acc2[m][nf] = __builtin_amdgcn_mfma_f32_16x16x32_bf16(a[m], b[nf], acc2[m][nf], 0, 0, 0);
  }

  // ---- epilogue ----
  if constexpr (PHASE == 4) {
    int c = wid * 16 + mrow;
    float bb = A.b2[c];
    #pragma unroll
    for (int m = 0; m < 4; ++m)
      #pragma unroll
      for (int j = 0; j < 4; ++j) {
        int rg = r0 + m * 16 + rbase + j;
        if (rg < M) A.outF[(size_t)rg * 128 + c] = acc2[m][0][j] + bb;   // fp32 out
      }
  } else {
    const int cc0 = wid * 32 + mrow;
    const int cc1 = cc0 + 16;
    const float bb0 = A.b2[cc0];
    const float bb1 = A.b2[cc1];
    // LN stats: 16-lane shfl reduce -> per-wave partials (overlay) -> combine.
    #pragma unroll
    for (int m = 0; m < 4; ++m)
      #pragma unroll
      for (int j = 0; j < 4; ++j) {
        acc2[m][0][j] += bb0;
        acc2[m][1][j] += bb1;
        float t  = acc2[m][0][j] + acc2[m][1][j];
        float t2 = acc2[m][0][j] * acc2[m][0][j] + acc2[m][1][j] * acc2[m][1][j];
        #pragma unroll
        for (int mk = 1; mk < 16; mk <<= 1) {
          t  += __shfl_xor(t, mk);
          t2 += __shfl_xor(t2, mk);
        }
        if (mrow == 0) {
          int row = m * 16 + rbase + j;
          ps [wid * 64 + row] = t;
          ps2[wid * 64 + row] = t2;
        }
      }
    __syncthreads();
    if (tid < 64) {
      float s = 0.f, q = 0.f;
      #pragma unroll
      for (int w = 0; w < 8; ++w) { s += ps[w * 64 + tid]; q += ps2[w * 64 + tid]; }
      float mu = s * (1.0f / 256.0f);
      float va = fmaxf(q * (1.0f / 256.0f) - mu * mu, 0.f);
      rs_mu[tid] = mu;
      rs_rs[tid] = rsqrtf(va + 1e-5f);
    }
    __syncthreads();
    const float ls0 = A.lns[cc0], lo0 = A.lno[cc0];
    const float ls1 = A.lns[cc1], lo1 = A.lno[cc1];
    #pragma unroll
    for (int m = 0; m < 4; ++m)
      #pragma unroll
      for (int j = 0; j < 4; ++j) {
        int row = m * 16 + rbase + j;
        int rg = r0 + row;
        if (rg >= M) continue;
        float mu = rs_mu[row], rstd = rs_rs[row];
        float y0 = (acc2[m][0][j] - mu) * rstd * ls0 + lo0;
        float y1 = (acc2[m][1][j] - mu) * rstd * ls1 + lo1;
        size_t base = (size_t)rg * 256;
        if constexpr (PHASE == 0) {
          A.nodeB[base + cc0] = f2bf(y0);
          A.nodeB[base + cc1] = f2bf(y1);
        } else if constexpr (PHASE == 1) {
          A.edgeB[base + cc0] = f2bf(y0);
          A.edgeB[base + cc1] = f2bf(y1);
        } else if constexpr (PHASE == 2) {
          A.edgeB[base + cc0] = f2bf(bf2f(A.edgeB[base + cc0]) + y0);
          A.edgeB[base + cc1] = f2bf(bf2f(A.edgeB[base + cc1]) + y1);
        } else {  // PHASE 3: node residual
          A.nodeB[base + cc0] = f2bf(bf2f(A.nodeB[base + cc0]) + y0);
          A.nodeB[base + cc1] = f2bf(bf2f(A.nodeB[base + cc1]) + y1);
        }
      }
  }
}

extern "C" void kernel_launch(void* const* d_in, const int* in_sizes, int n_in,
                              void* d_out, int out_size, void* d_ws, size_t ws_size,
                              hipStream_t stream) {
  (void)in_sizes; (void)n_in; (void)out_size; (void)ws_size;
  const float* x_node = (const float*)d_in[0];
  const float* x_edge = (const float*)d_in[1];
  const int* snd = (const int*)d_in[2];
  const int* rcv = (const int*)d_in[3];
  const float* en_w1 = (const float*)d_in[4];
  const float* en_b1 = (const float*)d_in[5];
  const float* en_w2 = (const float*)d_in[6];
  const float* en_b2 = (const float*)d_in[7];
  const float* en_ls = (const float*)d_in[8];
  const float* en_lo = (const float*)d_in[9];
  const float* ee_w1 = (const float*)d_in[10];
  const float* ee_b1 = (const float*)d_in[11];
  const float* ee_w2 = (const float*)d_in[12];
  const float* ee_b2 = (const float*)d_in[13];
  const float* ee_ls = (const float*)d_in[14];
  const float* ee_lo = (const float*)d_in[15];
  const float* pe_w1 = (const float*)d_in[16];
  const float* pe_b1 = (const float*)d_in[17];
  const float* pe_w2 = (const float*)d_in[18];
  const float* pe_b2 = (const float*)d_in[19];
  const float* pe_ls = (const float*)d_in[20];
  const float* pe_lo = (const float*)d_in[21];
  const float* pn_w1 = (const float*)d_in[22];
  const float* pn_b1 = (const float*)d_in[23];
  const float* pn_w2 = (const float*)d_in[24];
  const float* pn_b2 = (const float*)d_in[25];
  const float* pn_ls = (const float*)d_in[26];
  const float* pn_lo = (const float*)d_in[27];
  const float* dc_w1 = (const float*)d_in[28];
  const float* dc_b1 = (const float*)d_in[29];
  const float* dc_w2 = (const float*)d_in[30];
  const float* dc_b2 = (const float*)d_in[31];

  // ---- workspace: exactly 256,000,000 bytes ----
  char* ws = (char*)d_ws;
  unsigned short* edgeB = (unsigned short*)(ws);                  // 153,600,000 B
  unsigned short* nodeB = (unsigned short*)(ws + 153600000LL);    //  51,200,000 B
  unsigned short* aggB  = (unsigned short*)(ws + 204800000LL);    //  51,200,000 B

  // ---- packed bf16 weights + CSR scratch in d_out (51.2MB fp32 buffer) ----
  unsigned short* wpck = (unsigned short*)d_out;
  size_t o = 0;
  auto nxt = [&](size_t n) { unsigned short* p = wpck + o; o += n; return p; };
  unsigned short* p_en_w1 = nxt(128 * 256);
  unsigned short* p_en_w2 = nxt(256 * 256);
  unsigned short* p_ee_w1 = nxt(64 * 256);                 // Kpad 64
  unsigned short* p_ee_w2 = nxt(256 * 256);
  unsigned short* p_pe_w1 = nxt((size_t)6 * 768 * 256);
  unsigned short* p_pe_w2 = nxt((size_t)6 * 256 * 256);
  unsigned short* p_pn_w1 = nxt((size_t)6 * 512 * 256);
  unsigned short* p_pn_w2 = nxt((size_t)6 * 256 * 256);
  unsigned short* p_dc_w1 = nxt(256 * 256);     // dc block contiguous
  unsigned short* p_dc_w2 = nxt(256 * 128);
  const size_t DC_BYTES = (256 * 256 + 256 * 128) * 2;  // 196,608

  char* outc = (char*)d_out;
  int* cnt  = (int*)(outc + 6062080);    //   400,000 B
  int* cnt2 = (int*)(outc + 6462080);    //   400,000 B
  int* off  = (int*)(outc + 6862080);    //   400,004 B
  int* eidx = (int*)(outc + 7262096);    // 1,200,000 B (ends 8,462,096 < 51.2MB)

  dim3 B(512);
  pack_w<<<dim3(4 * 16, 1), B, 0, stream>>>(en_w1, p_en_w1, 128, 128, 256);
  pack_w<<<dim3(8 * 16, 1), B, 0, stream>>>(en_w2, p_en_w2, 256, 256, 256);
  pack_w<<<dim3(2 * 16, 1), B, 0, stream>>>(ee_w1, p_ee_w1, 4, 64, 256);
  pack_w<<<dim3(8 * 16, 1), B, 0, stream>>>(ee_w2, p_ee_w2, 256, 256, 256);
  pack_w<<<dim3(24 * 16, 6), B, 0, stream>>>(pe_w1, p_pe_w1, 768, 768, 256);
  pack_w<<<dim3(8 * 16, 6), B, 0, stream>>>(pe_w2, p_pe_w2, 256, 256, 256);
  pack_w<<<dim3(16 * 16, 6), B, 0, stream>>>(pn_w1, p_pn_w1, 512, 512, 256);
  pack_w<<<dim3(8 * 16, 6), B, 0, stream>>>(pn_w2, p_pn_w2, 256, 256, 256);
  pack_w<<<dim3(8 * 16, 1), B, 0, stream>>>(dc_w1, p_dc_w1, 256, 256, 256);
  pack_w<<<dim3(8 * 8, 1), B, 0, stream>>>(dc_w2, p_dc_w2, 256, 256, 128);

  // ---- CSR build (ints only; rebuilt every launch) ----
  zero_ws<<<dim3(196), dim3(256), 0, stream>>>((uint4*)cnt, 800000 / 16);
  hist_k<<<dim3(1172), dim3(256), 0, stream>>>(rcv, cnt);
  scan_k<<<dim3(1), dim3(1024), 0, stream>>>(cnt, off);
  fill_k<<<dim3(1172), dim3(256), 0, stream>>>(rcv, off, cnt2, eidx);

  dim3 GN(1563), GE(4688);

  { // encoder: nodes
    KArgs a{}; a.Xf = x_node; a.W1p = p_en_w1; a.W2p = p_en_w2;
    a.b1 = en_b1; a.b2 = en_b2; a.lns = en_ls; a.lno = en_lo;
    a.nodeB = nodeB; a.M = NN;
    gnn_kernel<0><<<GN, B, 0, stream>>>(a);
  }
  { // encoder: edges
    KArgs a{}; a.Xf = x_edge; a.W1p = p_ee_w1; a.W2p = p_ee_w2;
    a.b1 = ee_b1; a.b2 = ee_b2; a.lns = ee_ls; a.lno = ee_lo;
    a.edgeB = edgeB; a.M = NE;
    gnn_kernel<1><<<GE, B, 0, stream>>>(a);
  }
  for (int s = 0; s < 6; ++s) {
    { // edge update (in-place residual)
      KArgs a{}; a.snd = snd; a.rcv = rcv;
      a.nodeB = nodeB; a.edgeB = edgeB;
      a.W1p = p_pe_w1 + (size_t)s * 768 * 256;
      a.W2p = p_pe_w2 + (size_t)s * 256 * 256;
      a.b1 = pe_b1 + s * 256; a.b2 = pe_b2 + s * 256;
      a.lns = pe_ls + s * 256; a.lno = pe_lo + s * 256;
      a.M = NE;
      gnn_kernel<2><<<GE, B, 0, stream>>>(a);
    }
    // aggregate: CSR gather, fp32 accumulate
    agg_k<<<dim3(12500), dim3(256), 0, stream>>>(edgeB, off, eidx, aggB);
    { // node update (in-place residual)
      KArgs a{}; a.nodeB = nodeB; a.aggB = aggB;
      a.W1p = p_pn_w1 + (size_t)s * 512 * 256;
      a.W2p = p_pn_w2 + (size_t)s * 256 * 256;
      a.b1 = pn_b1 + s * 256; a.b2 = pn_b2 + s * 256;
      a.lns = pn_ls + s * 256; a.lno = pn_lo + s * 256;
      a.M = NN;
      gnn_kernel<3><<<GN, B, 0, stream>>>(a);
    }
  }
  // move decoder packed weights out of d_out (agg region is dead now)
  hipMemcpyAsync((void*)aggB, p_dc_w1, DC_BYTES, hipMemcpyDeviceToDevice, stream);
  { // decoder (overwrites all of d_out with fp32 output)
    KArgs a{}; a.nodeB = nodeB;
    a.W1p = (const unsigned short*)aggB;
    a.W2p = (const unsigned short*)aggB + 256 * 256;
    a.b1 = dc_b1; a.b2 = dc_b2;
    a.outF = (float*)d_out; a.M = NN;
    gnn_kernel<4><<<GN, B, 0, stream>>>(a);
  }
}